// Round 1
// baseline (1706.968 us; speedup 1.0000x reference)
//
#include <hip/hip_runtime.h>
#include <math.h>

#define NS 1024
#define NV 99
#define NPTS 100
#define H 512

// ---------------- K1: weight norm ----------------
// rows 0..511 mod0(len64) | 512..1023 mod1(576) | 1024..1535 mod2(576)
// 1536..2047 s1(512,transposed out) | 2048..2559 s2(512,transposed) | 2560..2562 dec(512)
__global__ __launch_bounds__(256) void k_wnorm(
    const float* __restrict__ mv0, const float* __restrict__ mg0,
    const float* __restrict__ mv1, const float* __restrict__ mg1,
    const float* __restrict__ mv2, const float* __restrict__ mg2,
    const float* __restrict__ sv1, const float* __restrict__ sg1,
    const float* __restrict__ sv2, const float* __restrict__ sg2,
    const float* __restrict__ dv,  const float* __restrict__ dg,
    float* __restrict__ wnM0, float* __restrict__ wnM1, float* __restrict__ wnM2,
    float* __restrict__ wnS1T, float* __restrict__ wnS2T, float* __restrict__ wnD)
{
    int rid = blockIdx.x, tid = threadIdx.x;
    const float* src; const float* g; float* dst; int len, tr = 0, j;
    if (rid < 512)       { j = rid;        src = mv0 + j*64;  g = mg0; dst = wnM0 + j*64;  len = 64;  }
    else if (rid < 1024) { j = rid - 512;  src = mv1 + j*576; g = mg1; dst = wnM1 + j*576; len = 576; }
    else if (rid < 1536) { j = rid - 1024; src = mv2 + j*576; g = mg2; dst = wnM2 + j*576; len = 576; }
    else if (rid < 2048) { j = rid - 1536; src = sv1 + j*512; g = sg1; dst = wnS1T + j;    len = 512; tr = 1; }
    else if (rid < 2560) { j = rid - 2048; src = sv2 + j*512; g = sg2; dst = wnS2T + j;    len = 512; tr = 1; }
    else                 { j = rid - 2560; src = dv  + j*512; g = dg;  dst = wnD + j*512;  len = 512; }

    float ss = 0.f;
    for (int k = tid; k < len; k += 256) { float v = src[k]; ss += v * v; }
    __shared__ float red[4];
    __shared__ float s_scale;
    for (int o = 32; o > 0; o >>= 1) ss += __shfl_down(ss, o);
    if ((tid & 63) == 0) red[tid >> 6] = ss;
    __syncthreads();
    if (tid == 0) s_scale = g[j] * rsqrtf(red[0] + red[1] + red[2] + red[3]);
    __syncthreads();
    float sc = s_scale;
    if (tr) { for (int k = tid; k < len; k += 256) dst[(size_t)k * 512] = src[k] * sc; }
    else    { for (int k = tid; k < len; k += 256) dst[k] = src[k] * sc; }
}

// ---------------- K2: siren layer-0 table: sin(30*(t_p*w0_j + b0_j)) ----------------
__global__ __launch_bounds__(256) void k_s0(
    const float* __restrict__ sv0, const float* __restrict__ sg0,
    const float* __restrict__ sb0, float* __restrict__ s0sin)
{
    int idx = blockIdx.x * 256 + threadIdx.x;
    if (idx >= NV * H) return;
    int p = idx >> 9, j = idx & 511;
    float v = sv0[j];
    float w = sg0[j] * v * rsqrtf(v * v);   // g * v / |v|
    float t = (float)p / 99.0f;
    s0sin[idx] = __sinf(30.0f * (t * w + sb0[j]));
}

// ---------------- K3: modulation branch (per strand) ----------------
__global__ __launch_bounds__(256) void k_mod(
    const float* __restrict__ sf,
    const float* __restrict__ wnM0, const float* __restrict__ mb0,
    const float* __restrict__ wnM1, const float* __restrict__ mb1,
    const float* __restrict__ wnM2, const float* __restrict__ mb2,
    float* __restrict__ onem)   // [3][NS][H] = 1 - silu(...)
{
    int s = blockIdx.x, tid = threadIdx.x;
    __shared__ float z[576];
    __shared__ float mt[512];
    for (int k = tid; k < 64; k += 256) z[k] = sf[s * 64 + k];
    __syncthreads();
    // layer 0 (in = 64)
#pragma unroll
    for (int r = 0; r < 2; ++r) {
        int j = tid + 256 * r;
        const float* wr = wnM0 + j * 64;
        float a0 = 0, a1 = 0, a2 = 0, a3 = 0;
#pragma unroll
        for (int k = 0; k < 64; k += 4) {
            float4 w = *(const float4*)(wr + k);
            a0 += z[k] * w.x; a1 += z[k+1] * w.y; a2 += z[k+2] * w.z; a3 += z[k+3] * w.w;
        }
        float acc = (a0 + a1) + (a2 + a3) + mb0[j];
        float m = acc / (1.f + __expf(-acc));
        onem[s * H + j] = 1.f - m;
        mt[j] = m;
    }
    __syncthreads();
    for (int k = tid; k < 512; k += 256) z[64 + k] = mt[k];
    __syncthreads();
    // layer 1 (in = 576)
#pragma unroll
    for (int r = 0; r < 2; ++r) {
        int j = tid + 256 * r;
        const float* wr = wnM1 + j * 576;
        float a0 = 0, a1 = 0, a2 = 0, a3 = 0;
        for (int k = 0; k < 576; k += 4) {
            float4 w = *(const float4*)(wr + k);
            a0 += z[k] * w.x; a1 += z[k+1] * w.y; a2 += z[k+2] * w.z; a3 += z[k+3] * w.w;
        }
        float acc = (a0 + a1) + (a2 + a3) + mb1[j];
        float m = acc / (1.f + __expf(-acc));
        onem[NS * H + s * H + j] = 1.f - m;
        mt[j] = m;
    }
    __syncthreads();
    for (int k = tid; k < 512; k += 256) z[64 + k] = mt[k];
    __syncthreads();
    // layer 2 (in = 576)
#pragma unroll
    for (int r = 0; r < 2; ++r) {
        int j = tid + 256 * r;
        const float* wr = wnM2 + j * 576;
        float a0 = 0, a1 = 0, a2 = 0, a3 = 0;
        for (int k = 0; k < 576; k += 4) {
            float4 w = *(const float4*)(wr + k);
            a0 += z[k] * w.x; a1 += z[k+1] * w.y; a2 += z[k+2] * w.z; a3 += z[k+3] * w.w;
        }
        float acc = (a0 + a1) + (a2 + a3) + mb2[j];
        float m = acc / (1.f + __expf(-acc));
        onem[2 * NS * H + s * H + j] = 1.f - m;
    }
}

// ---------------- K4: main fused siren layers 1,2 + decoder ----------------
// Block: 256 threads, 24 rows (global row = strand*99 + point), all 512 cols.
// hT[k][p] transposed in LDS (57 KB -> 2 blocks/CU). W read from global (L2, K-major, coalesced).
#define TP 24
#define PPAD 28
__global__ __launch_bounds__(256) void k_main(
    const float* __restrict__ wnS1T, const float* __restrict__ wnS2T,
    const float* __restrict__ wnD,
    const float* __restrict__ sb1, const float* __restrict__ sb2,
    const float* __restrict__ db,
    const float* __restrict__ s0sin, const float* __restrict__ onem,
    float* __restrict__ dirs)
{
    __shared__ float hT[512][PPAD];
    int tid = threadIdx.x;
    int tp = tid >> 6, tj = tid & 63;
    int row0 = blockIdx.x * TP;

    // fill: h1^T[j][rp] = (1-m0[s][j]) * s0sin[p][j]
#pragma unroll
    for (int it = 0; it < (TP * H) / 256; ++it) {
        int idx = it * 256 + tid;
        int j = idx & 511, rp = idx >> 9;
        int row = row0 + rp, s = row / 99, p = row - s * 99;
        hT[j][rp] = onem[s * H + j] * s0sin[p * H + j];
    }
    __syncthreads();

    int pa[6];
    pa[0] = 4*tp; pa[1] = 4*tp+1; pa[2] = 4*tp+2; pa[3] = 4*tp+3;
    pa[4] = 16 + 2*tp; pa[5] = 17 + 2*tp;
    int jb[8];
#pragma unroll
    for (int b = 0; b < 4; ++b) { jb[b] = 4*tj + b; jb[4+b] = 256 + 4*tj + b; }

    float acc[6][8];
    for (int layer = 0; layer < 2; ++layer) {
        const float* WT = layer ? wnS2T : wnS1T;
        const float* om = onem + (layer + 1) * NS * H;
        const float* bb = layer ? sb2 : sb1;
#pragma unroll
        for (int a = 0; a < 6; ++a)
#pragma unroll
            for (int b = 0; b < 8; ++b) acc[a][b] = 0.f;

#pragma unroll 8
        for (int k = 0; k < 512; ++k) {
            float4 w0 = *(const float4*)(WT + k * H + 4 * tj);
            float4 w1 = *(const float4*)(WT + k * H + 256 + 4 * tj);
            float4 h0 = *(const float4*)&hT[k][4 * tp];
            float2 h1 = *(const float2*)&hT[k][16 + 2 * tp];
            float hv[6] = { h0.x, h0.y, h0.z, h0.w, h1.x, h1.y };
            float wv[8] = { w0.x, w0.y, w0.z, w0.w, w1.x, w1.y, w1.z, w1.w };
#pragma unroll
            for (int a = 0; a < 6; ++a)
#pragma unroll
                for (int b = 0; b < 8; ++b) acc[a][b] += hv[a] * wv[b];
        }
        __syncthreads();   // all hT reads done before overwrite

        float bbv[8];
#pragma unroll
        for (int b = 0; b < 8; ++b) bbv[b] = bb[jb[b]];
#pragma unroll
        for (int a = 0; a < 6; ++a) {
            int row = row0 + pa[a], s = row / 99;
#pragma unroll
            for (int b = 0; b < 8; ++b) {
                float hp = om[s * H + jb[b]] * __sinf(acc[a][b] + bbv[b]);
                acc[a][b] = hp;
                if (layer == 0) hT[jb[b]][pa[a]] = hp;
            }
        }
        __syncthreads();
    }

    // decoder: dirs[row][c] = 0.01*(sum_j wnD[c][j]*h3[row][j] + db[c])
    float part[6][3];
#pragma unroll
    for (int a = 0; a < 6; ++a) { part[a][0] = 0; part[a][1] = 0; part[a][2] = 0; }
#pragma unroll
    for (int b = 0; b < 8; ++b) {
        float w0 = wnD[jb[b]], w1 = wnD[H + jb[b]], w2 = wnD[2 * H + jb[b]];
#pragma unroll
        for (int a = 0; a < 6; ++a) {
            part[a][0] += acc[a][b] * w0;
            part[a][1] += acc[a][b] * w1;
            part[a][2] += acc[a][b] * w2;
        }
    }
    float d0 = db[0], d1 = db[1], d2 = db[2];
#pragma unroll
    for (int a = 0; a < 6; ++a) {
        float v0 = part[a][0], v1 = part[a][1], v2 = part[a][2];
        for (int o = 32; o > 0; o >>= 1) {
            v0 += __shfl_down(v0, o); v1 += __shfl_down(v1, o); v2 += __shfl_down(v2, o);
        }
        if (tj == 0) {
            int row = row0 + pa[a];
            dirs[row * 3 + 0] = 0.01f * (v0 + d0);
            dirs[row * 3 + 1] = 0.01f * (v1 + d1);
            dirs[row * 3 + 2] = 0.01f * (v2 + d2);
        }
    }
}

// ---------------- K5: cumsum + output ----------------
__global__ __launch_bounds__(256) void k_cumsum(const float* __restrict__ dirs,
                                                float* __restrict__ out)
{
    int idx = blockIdx.x * 256 + threadIdx.x;   // strand*3 + c
    if (idx >= NS * 3) return;
    int s = idx / 3, c = idx - 3 * s;
    float acc = 0.f;
    out[(s * NPTS + 0) * 3 + c] = 0.f;
    for (int p = 0; p < NV; ++p) {
        acc += dirs[(s * NV + p) * 3 + c];
        out[(s * NPTS + p + 1) * 3 + c] = acc;
    }
}

extern "C" void kernel_launch(void* const* d_in, const int* in_sizes, int n_in,
                              void* d_out, int out_size, void* d_ws, size_t ws_size,
                              hipStream_t stream)
{
    const float* sf  = (const float*)d_in[0];
    const float* mv0 = (const float*)d_in[1];  const float* mg0 = (const float*)d_in[2];  const float* mb0 = (const float*)d_in[3];
    const float* mv1 = (const float*)d_in[4];  const float* mg1 = (const float*)d_in[5];  const float* mb1 = (const float*)d_in[6];
    const float* mv2 = (const float*)d_in[7];  const float* mg2 = (const float*)d_in[8];  const float* mb2 = (const float*)d_in[9];
    const float* sv0 = (const float*)d_in[10]; const float* sg0 = (const float*)d_in[11]; const float* sb0 = (const float*)d_in[12];
    const float* sv1 = (const float*)d_in[13]; const float* sg1 = (const float*)d_in[14]; const float* sb1 = (const float*)d_in[15];
    const float* sv2 = (const float*)d_in[16]; const float* sg2 = (const float*)d_in[17]; const float* sb2 = (const float*)d_in[18];
    const float* dv  = (const float*)d_in[19]; const float* dg  = (const float*)d_in[20]; const float* dbv = (const float*)d_in[21];

    float* ws = (float*)d_ws;
    float* wnS1T = ws;                 // 262144
    float* wnS2T = ws + 262144;        // 262144
    float* wnD   = ws + 524288;        // 1536
    float* s0sin = ws + 525824;        // 50688
    float* onem  = ws + 576512;        // 3*1024*512 = 1572864
    float* dirs  = ws + 2149376;       // 101376*3 = 304128
    float* wnM0  = ws + 2453504;       // 32768
    float* wnM1  = ws + 2486272;       // 294912
    float* wnM2  = ws + 2781184;       // 294912  (end: 3076096 floats = 12.3 MB)

    hipLaunchKernelGGL(k_wnorm, dim3(2563), dim3(256), 0, stream,
                       mv0, mg0, mv1, mg1, mv2, mg2, sv1, sg1, sv2, sg2, dv, dg,
                       wnM0, wnM1, wnM2, wnS1T, wnS2T, wnD);
    hipLaunchKernelGGL(k_s0, dim3(198), dim3(256), 0, stream, sv0, sg0, sb0, s0sin);
    hipLaunchKernelGGL(k_mod, dim3(1024), dim3(256), 0, stream,
                       sf, wnM0, mb0, wnM1, mb1, wnM2, mb2, onem);
    hipLaunchKernelGGL(k_main, dim3((NS * NV) / TP), dim3(256), 0, stream,
                       wnS1T, wnS2T, wnD, sb1, sb2, dbv, s0sin, onem, dirs);
    hipLaunchKernelGGL(k_cumsum, dim3(12), dim3(256), 0, stream, dirs, (float*)d_out);
}

// Round 2
// 994.252 us; speedup vs baseline: 1.7168x; 1.7168x over previous
//
#include <hip/hip_runtime.h>
#include <math.h>

#define NS 1024
#define NV 99
#define NPTS 100
#define H 512

typedef __bf16 bf16x8 __attribute__((ext_vector_type(8)));
typedef float f32x4 __attribute__((ext_vector_type(4)));

// ---------------- K1: weight norm ----------------
// rows 0..511 mod0(len64) | 512..1023 mod1(576) | 1024..1535 mod2(576)
// 1536..2047 s1 -> bf16 row-major | 2048..2559 s2 -> bf16 row-major | 2560..2562 dec(fp32)
__global__ __launch_bounds__(256) void k_wnorm(
    const float* __restrict__ mv0, const float* __restrict__ mg0,
    const float* __restrict__ mv1, const float* __restrict__ mg1,
    const float* __restrict__ mv2, const float* __restrict__ mg2,
    const float* __restrict__ sv1, const float* __restrict__ sg1,
    const float* __restrict__ sv2, const float* __restrict__ sg2,
    const float* __restrict__ dv,  const float* __restrict__ dg,
    float* __restrict__ wnM0, float* __restrict__ wnM1, float* __restrict__ wnM2,
    __bf16* __restrict__ W1b, __bf16* __restrict__ W2b, float* __restrict__ wnD)
{
    int rid = blockIdx.x, tid = threadIdx.x;
    const float* src; const float* g; int len, j;
    float* dstf = nullptr; __bf16* dstb = nullptr;
    if (rid < 512)       { j = rid;        src = mv0 + j*64;  g = mg0; dstf = wnM0 + j*64;  len = 64;  }
    else if (rid < 1024) { j = rid - 512;  src = mv1 + j*576; g = mg1; dstf = wnM1 + j*576; len = 576; }
    else if (rid < 1536) { j = rid - 1024; src = mv2 + j*576; g = mg2; dstf = wnM2 + j*576; len = 576; }
    else if (rid < 2048) { j = rid - 1536; src = sv1 + j*512; g = sg1; dstb = W1b + j*512;  len = 512; }
    else if (rid < 2560) { j = rid - 2048; src = sv2 + j*512; g = sg2; dstb = W2b + j*512;  len = 512; }
    else                 { j = rid - 2560; src = dv  + j*512; g = dg;  dstf = wnD + j*512;  len = 512; }

    float ss = 0.f;
    for (int k = tid; k < len; k += 256) { float v = src[k]; ss += v * v; }
    __shared__ float red[4];
    __shared__ float s_scale;
    for (int o = 32; o > 0; o >>= 1) ss += __shfl_down(ss, o);
    if ((tid & 63) == 0) red[tid >> 6] = ss;
    __syncthreads();
    if (tid == 0) s_scale = g[j] * rsqrtf(red[0] + red[1] + red[2] + red[3]);
    __syncthreads();
    float sc = s_scale;
    if (dstb) { for (int k = tid; k < len; k += 256) dstb[k] = (__bf16)(src[k] * sc); }
    else      { for (int k = tid; k < len; k += 256) dstf[k] = src[k] * sc; }
}

// ---------------- K2: siren layer-0 table: sin(30*(t_p*w0_j + b0_j)) ----------------
__global__ __launch_bounds__(256) void k_s0(
    const float* __restrict__ sv0, const float* __restrict__ sg0,
    const float* __restrict__ sb0, float* __restrict__ s0sin)
{
    int idx = blockIdx.x * 256 + threadIdx.x;
    if (idx >= NV * H) return;
    int p = idx >> 9, j = idx & 511;
    float v = sv0[j];
    float w = sg0[j] * v * rsqrtf(v * v);   // g * v / |v|
    float t = (float)p / 99.0f;
    s0sin[idx] = __sinf(30.0f * (t * w + sb0[j]));
}

// ---------------- K3: modulation branch (per strand) ----------------
__global__ __launch_bounds__(256) void k_mod(
    const float* __restrict__ sf,
    const float* __restrict__ wnM0, const float* __restrict__ mb0,
    const float* __restrict__ wnM1, const float* __restrict__ mb1,
    const float* __restrict__ wnM2, const float* __restrict__ mb2,
    float* __restrict__ onem)   // [3][NS][H] = 1 - silu(...)
{
    int s = blockIdx.x, tid = threadIdx.x;
    __shared__ float z[576];
    __shared__ float mt[512];
    for (int k = tid; k < 64; k += 256) z[k] = sf[s * 64 + k];
    __syncthreads();
#pragma unroll
    for (int r = 0; r < 2; ++r) {
        int j = tid + 256 * r;
        const float* wr = wnM0 + j * 64;
        float a0 = 0, a1 = 0, a2 = 0, a3 = 0;
#pragma unroll
        for (int k = 0; k < 64; k += 4) {
            float4 w = *(const float4*)(wr + k);
            a0 += z[k] * w.x; a1 += z[k+1] * w.y; a2 += z[k+2] * w.z; a3 += z[k+3] * w.w;
        }
        float acc = (a0 + a1) + (a2 + a3) + mb0[j];
        float m = acc / (1.f + __expf(-acc));
        onem[s * H + j] = 1.f - m;
        mt[j] = m;
    }
    __syncthreads();
    for (int k = tid; k < 512; k += 256) z[64 + k] = mt[k];
    __syncthreads();
#pragma unroll
    for (int r = 0; r < 2; ++r) {
        int j = tid + 256 * r;
        const float* wr = wnM1 + j * 576;
        float a0 = 0, a1 = 0, a2 = 0, a3 = 0;
        for (int k = 0; k < 576; k += 4) {
            float4 w = *(const float4*)(wr + k);
            a0 += z[k] * w.x; a1 += z[k+1] * w.y; a2 += z[k+2] * w.z; a3 += z[k+3] * w.w;
        }
        float acc = (a0 + a1) + (a2 + a3) + mb1[j];
        float m = acc / (1.f + __expf(-acc));
        onem[NS * H + s * H + j] = 1.f - m;
        mt[j] = m;
    }
    __syncthreads();
    for (int k = tid; k < 512; k += 256) z[64 + k] = mt[k];
    __syncthreads();
#pragma unroll
    for (int r = 0; r < 2; ++r) {
        int j = tid + 256 * r;
        const float* wr = wnM2 + j * 576;
        float a0 = 0, a1 = 0, a2 = 0, a3 = 0;
        for (int k = 0; k < 576; k += 4) {
            float4 w = *(const float4*)(wr + k);
            a0 += z[k] * w.x; a1 += z[k+1] * w.y; a2 += z[k+2] * w.z; a3 += z[k+3] * w.w;
        }
        float acc = (a0 + a1) + (a2 + a3) + mb2[j];
        float m = acc / (1.f + __expf(-acc));
        onem[2 * NS * H + s * H + j] = 1.f - m;
    }
}

// ---------------- K4: main fused siren layers 1,2 + decoder (bf16 MFMA) ----------------
// 1 wave per block, 32 rows (2 x 16-row A tiles), all 512 cols.
// A-strips (full K) in registers; B streamed from global bf16 W (row-major:
// B[n=lane&15][k=quad*8+j] = W[n][k] -> 8 contiguous bf16 = 16B load).
// C/D layout: col=lane&15, row=quad*4+reg. Layer1->2 transpose via 32KB LDS.
__global__ __launch_bounds__(64, 1) void k_main(
    const __bf16* __restrict__ W1b, const __bf16* __restrict__ W2b,
    const float* __restrict__ wnD, const float* __restrict__ sb1,
    const float* __restrict__ sb2, const float* __restrict__ db,
    const float* __restrict__ s0sin, const float* __restrict__ onem,
    float* __restrict__ dirs)
{
    __shared__ __bf16 h2s[32][512];   // 32 KB
    const int lane = threadIdx.x;
    const int m = lane & 15, quad = lane >> 4;
    const int rowbase = blockIdx.x * 32;

    // ---- build layer-1 A strips: h1[r][k] = onem0[s(r)][k] * s0sin[p(r)][k] ----
    bf16x8 A0[16], A1[16];
    {
        const int r0 = rowbase + m, r1 = r0 + 16;
        const int sA = r0 / 99, pA = r0 - sA * 99;
        const int sB = r1 / 99, pB = r1 - sB * 99;
        const float* omA = onem + sA * H;
        const float* tsA = s0sin + pA * H;
        const float* omB = onem + sB * H;
        const float* tsB = s0sin + pB * H;
#pragma unroll
        for (int kb = 0; kb < 16; ++kb) {
            const int k0 = kb * 32 + quad * 8;
            f32x4 oa = *(const f32x4*)(omA + k0);
            f32x4 ob = *(const f32x4*)(omA + k0 + 4);
            f32x4 ta = *(const f32x4*)(tsA + k0);
            f32x4 tb = *(const f32x4*)(tsA + k0 + 4);
            bf16x8 v;
            v[0] = (__bf16)(oa[0] * ta[0]); v[1] = (__bf16)(oa[1] * ta[1]);
            v[2] = (__bf16)(oa[2] * ta[2]); v[3] = (__bf16)(oa[3] * ta[3]);
            v[4] = (__bf16)(ob[0] * tb[0]); v[5] = (__bf16)(ob[1] * tb[1]);
            v[6] = (__bf16)(ob[2] * tb[2]); v[7] = (__bf16)(ob[3] * tb[3]);
            A0[kb] = v;
            oa = *(const f32x4*)(omB + k0);
            ob = *(const f32x4*)(omB + k0 + 4);
            ta = *(const f32x4*)(tsB + k0);
            tb = *(const f32x4*)(tsB + k0 + 4);
            v[0] = (__bf16)(oa[0] * ta[0]); v[1] = (__bf16)(oa[1] * ta[1]);
            v[2] = (__bf16)(oa[2] * ta[2]); v[3] = (__bf16)(oa[3] * ta[3]);
            v[4] = (__bf16)(ob[0] * tb[0]); v[5] = (__bf16)(ob[1] * tb[1]);
            v[6] = (__bf16)(ob[2] * tb[2]); v[7] = (__bf16)(ob[3] * tb[3]);
            A1[kb] = v;
        }
    }

    // ---- layer 1: S1 = h1 @ W1^T; h2 = (1-m1)*sin(S1+b1) -> LDS ----
    const float* om1 = onem + NS * H;
#pragma unroll 2
    for (int ct = 0; ct < 32; ++ct) {
        const int col = ct * 16 + m;
        const __bf16* wp = W1b + col * H + quad * 8;
        f32x4 acc0 = {0.f, 0.f, 0.f, 0.f}, acc1 = {0.f, 0.f, 0.f, 0.f};
#pragma unroll
        for (int kb = 0; kb < 16; ++kb) {
            bf16x8 b = *(const bf16x8*)(wp + kb * 32);
            acc0 = __builtin_amdgcn_mfma_f32_16x16x32_bf16(A0[kb], b, acc0, 0, 0, 0);
            acc1 = __builtin_amdgcn_mfma_f32_16x16x32_bf16(A1[kb], b, acc1, 0, 0, 0);
        }
        const float bias = sb1[col];
#pragma unroll
        for (int reg = 0; reg < 4; ++reg) {
            const int rr0 = rowbase + quad * 4 + reg;
            const int rr1 = rr0 + 16;
            const float h0 = om1[(rr0 / 99) * H + col] * __sinf(acc0[reg] + bias);
            const float h1 = om1[(rr1 / 99) * H + col] * __sinf(acc1[reg] + bias);
            h2s[quad * 4 + reg][col] = (__bf16)h0;
            h2s[16 + quad * 4 + reg][col] = (__bf16)h1;
        }
    }
    __syncthreads();

    // ---- reload A strips (layer-2 input) from LDS in A-layout ----
#pragma unroll
    for (int kb = 0; kb < 16; ++kb) {
        const int k0 = kb * 32 + quad * 8;
        A0[kb] = *(const bf16x8*)&h2s[m][k0];
        A1[kb] = *(const bf16x8*)&h2s[16 + m][k0];
    }

    // ---- layer 2 + fused decoder partials ----
    const float* om2 = onem + 2 * NS * H;
    float pd[24];
#pragma unroll
    for (int i = 0; i < 24; ++i) pd[i] = 0.f;
#pragma unroll 2
    for (int ct = 0; ct < 32; ++ct) {
        const int col = ct * 16 + m;
        const __bf16* wp = W2b + col * H + quad * 8;
        f32x4 acc0 = {0.f, 0.f, 0.f, 0.f}, acc1 = {0.f, 0.f, 0.f, 0.f};
#pragma unroll
        for (int kb = 0; kb < 16; ++kb) {
            bf16x8 b = *(const bf16x8*)(wp + kb * 32);
            acc0 = __builtin_amdgcn_mfma_f32_16x16x32_bf16(A0[kb], b, acc0, 0, 0, 0);
            acc1 = __builtin_amdgcn_mfma_f32_16x16x32_bf16(A1[kb], b, acc1, 0, 0, 0);
        }
        const float bias = sb2[col];
        const float w0 = wnD[col], w1 = wnD[H + col], w2 = wnD[2 * H + col];
#pragma unroll
        for (int reg = 0; reg < 4; ++reg) {
            const int rr0 = rowbase + quad * 4 + reg;
            const int rr1 = rr0 + 16;
            const float h0 = om2[(rr0 / 99) * H + col] * __sinf(acc0[reg] + bias);
            const float h1 = om2[(rr1 / 99) * H + col] * __sinf(acc1[reg] + bias);
            pd[reg]      += h0 * w0; pd[4 + reg]  += h0 * w1; pd[8 + reg]  += h0 * w2;
            pd[12 + reg] += h1 * w0; pd[16 + reg] += h1 * w1; pd[20 + reg] += h1 * w2;
        }
    }

    // reduce over the 16 lanes (m) within each quad group
#pragma unroll
    for (int i = 0; i < 24; ++i) {
        float v = pd[i];
        v += __shfl_xor(v, 1); v += __shfl_xor(v, 2);
        v += __shfl_xor(v, 4); v += __shfl_xor(v, 8);
        pd[i] = v;
    }
    if (m == 0) {
        const float d0 = db[0], d1 = db[1], d2 = db[2];
#pragma unroll
        for (int reg = 0; reg < 4; ++reg) {
            const int rr0 = rowbase + quad * 4 + reg;
            const int rr1 = rr0 + 16;
            dirs[rr0 * 3 + 0] = 0.01f * (pd[reg]      + d0);
            dirs[rr0 * 3 + 1] = 0.01f * (pd[4 + reg]  + d1);
            dirs[rr0 * 3 + 2] = 0.01f * (pd[8 + reg]  + d2);
            dirs[rr1 * 3 + 0] = 0.01f * (pd[12 + reg] + d0);
            dirs[rr1 * 3 + 1] = 0.01f * (pd[16 + reg] + d1);
            dirs[rr1 * 3 + 2] = 0.01f * (pd[20 + reg] + d2);
        }
    }
}

// ---------------- K5: cumsum + output ----------------
__global__ __launch_bounds__(256) void k_cumsum(const float* __restrict__ dirs,
                                                float* __restrict__ out)
{
    int idx = blockIdx.x * 256 + threadIdx.x;   // strand*3 + c
    if (idx >= NS * 3) return;
    int s = idx / 3, c = idx - 3 * s;
    float acc = 0.f;
    out[(s * NPTS + 0) * 3 + c] = 0.f;
    for (int p = 0; p < NV; ++p) {
        acc += dirs[(s * NV + p) * 3 + c];
        out[(s * NPTS + p + 1) * 3 + c] = acc;
    }
}

extern "C" void kernel_launch(void* const* d_in, const int* in_sizes, int n_in,
                              void* d_out, int out_size, void* d_ws, size_t ws_size,
                              hipStream_t stream)
{
    const float* sf  = (const float*)d_in[0];
    const float* mv0 = (const float*)d_in[1];  const float* mg0 = (const float*)d_in[2];  const float* mb0 = (const float*)d_in[3];
    const float* mv1 = (const float*)d_in[4];  const float* mg1 = (const float*)d_in[5];  const float* mb1 = (const float*)d_in[6];
    const float* mv2 = (const float*)d_in[7];  const float* mg2 = (const float*)d_in[8];  const float* mb2 = (const float*)d_in[9];
    const float* sv0 = (const float*)d_in[10]; const float* sg0 = (const float*)d_in[11]; const float* sb0 = (const float*)d_in[12];
    const float* sv1 = (const float*)d_in[13]; const float* sg1 = (const float*)d_in[14]; const float* sb1 = (const float*)d_in[15];
    const float* sv2 = (const float*)d_in[16]; const float* sg2 = (const float*)d_in[17]; const float* sb2 = (const float*)d_in[18];
    const float* dv  = (const float*)d_in[19]; const float* dg  = (const float*)d_in[20]; const float* dbv = (const float*)d_in[21];

    float* ws = (float*)d_ws;
    float* wnM0  = ws;                 // 32768
    float* wnM1  = ws + 32768;         // 294912
    float* wnM2  = ws + 327680;        // 294912
    float* wnD   = ws + 622592;        // 1536
    float* s0sin = ws + 624128;        // 50688
    float* onem  = ws + 674816;        // 1572864
    float* dirs  = ws + 2247680;       // 304128
    __bf16* W1b  = (__bf16*)(ws + 2551808);   // 512 KB
    __bf16* W2b  = W1b + 262144;              // 512 KB (end: ~11.26 MB)

    hipLaunchKernelGGL(k_wnorm, dim3(2563), dim3(256), 0, stream,
                       mv0, mg0, mv1, mg1, mv2, mg2, sv1, sg1, sv2, sg2, dv, dg,
                       wnM0, wnM1, wnM2, W1b, W2b, wnD);
    hipLaunchKernelGGL(k_s0, dim3(198), dim3(256), 0, stream, sv0, sg0, sb0, s0sin);
    hipLaunchKernelGGL(k_mod, dim3(1024), dim3(256), 0, stream,
                       sf, wnM0, mb0, wnM1, mb1, wnM2, mb2, onem);
    hipLaunchKernelGGL(k_main, dim3((NS * NV) / 32), dim3(64), 0, stream,
                       W1b, W2b, wnD, sb1, sb2, dbv, s0sin, onem, dirs);
    hipLaunchKernelGGL(k_cumsum, dim3(12), dim3(256), 0, stream, dirs, (float*)d_out);
}